// Round 2
// baseline (378.478 us; speedup 1.0000x reference)
//
#include <hip/hip_runtime.h>
#include <hip/hip_bf16.h>
#include <stdint.h>

typedef unsigned short u16;
typedef unsigned int u32;
typedef __attribute__((ext_vector_type(8))) short bf16x8;   // 8 bf16 in 4 VGPRs
typedef __attribute__((ext_vector_type(4))) float f32x4;

#define S_LEN 2048
#define D_DIM 1024
#define H_DIM 1024
#define BATCH 8
#define M_TOTAL (BATCH * S_LEN)   // 16384

__device__ __forceinline__ u16 f2b(float f) {
  u32 u = __builtin_bit_cast(u32, f);
  u32 r = (u + 0x7fffu + ((u >> 16) & 1u)) >> 16;   // RNE
  return (u16)r;
}

// ---------------- cast x (fp32 -> bf16), 8 elems/thread ----------------
__global__ __launch_bounds__(256) void cast_x_kernel(const float* __restrict__ in,
                                                     u16* __restrict__ out, int n8) {
  int i = blockIdx.x * 256 + threadIdx.x;
  if (i >= n8) return;
  const float4* p = (const float4*)in;
  float4 a = p[2 * i], b = p[2 * i + 1];
  u32 w0 = (u32)f2b(a.x) | ((u32)f2b(a.y) << 16);
  u32 w1 = (u32)f2b(a.z) | ((u32)f2b(a.w) << 16);
  u32 w2 = (u32)f2b(b.x) | ((u32)f2b(b.y) << 16);
  u32 w3 = (u32)f2b(b.z) | ((u32)f2b(b.w) << 16);
  ((uint4*)out)[i] = make_uint4(w0, w1, w2, w3);
}

// --- transpose-cast all 3 weights; z=0:Wq z=1:Wk (into concat Wtqk) z=2:Wv
__global__ __launch_bounds__(256) void wcast_all_kernel(
    const float* __restrict__ Wq, const float* __restrict__ Wk,
    const float* __restrict__ Wv, const float* __restrict__ bq,
    const float* __restrict__ bk, u16* __restrict__ Wtqk,
    u16* __restrict__ Wtv, float* __restrict__ bqk, float* __restrict__ lsum) {
  __shared__ float tile[32][33];
  int z = blockIdx.z;
  const float* W = (z == 0) ? Wq : (z == 1) ? Wk : Wv;
  u16* Wt = (z == 0) ? Wtqk : (z == 1) ? (Wtqk + 1024 * 1024) : Wtv;
  int h0 = blockIdx.x * 32, d0 = blockIdx.y * 32;
  int tx = threadIdx.x & 31, ty = threadIdx.x >> 5;
#pragma unroll
  for (int r = ty; r < 32; r += 8)
    tile[r][tx] = W[(size_t)(d0 + r) * H_DIM + h0 + tx];
  if (blockIdx.x == 0 && blockIdx.y == 0) {
    if (z == 0) {
      for (int i = threadIdx.x; i < 1024; i += 256) bqk[i] = bq[i];
    } else if (z == 1) {
      for (int i = threadIdx.x; i < 1024; i += 256) bqk[1024 + i] = bk[i];
    } else {
      for (int i = threadIdx.x; i < M_TOTAL; i += 256) lsum[i] = 0.f;
    }
  }
  __syncthreads();
#pragma unroll
  for (int r = ty; r < 32; r += 8)
    Wt[(size_t)(h0 + r) * D_DIM + d0 + tx] = f2b(tile[tx][r]);
}

// ---------------- GEMM 256x256 tile, 8 waves (2Mx4N of 128x64), BK=64 ----------------
// RACE FIX vs round 1: every wave's first read of a tile touches ALL FOUR staged
// halves (wm=128 waves read A rows 128-255 in phase 1; wn>=128 waves read B rows
// 128-255). So per-half counted publication is impossible with this wave map.
// Correct scheme: issue ALL of tile t+1's staging during phases 1-2 of tile t
// (early-issue), then ONE vmcnt(0)+s_barrier at the tile boundary. At that point
// the only outstanding loads are tile t+1's, issued a whole tile of compute
// earlier -> vmcnt(0) is exact and nearly free. One barrier per K-tile.
// Rule #18: every inline-asm wait is followed by sched_barrier(0) so MFMAs can't
// be hoisted above their data wait; no fences after MFMA bursts, so the compiler
// may interleave next-phase ds_reads / stage issues into the MFMA cluster.
// BIAS: 0 none, 1 bias[col], 2 bias[row].
// EPI:  0 plain, 1 exp(acc*scale)->bf16 + row-sum atomics into lsum,
//       2 acc * 1/lsum[row] (softmax normalize).
template <int BIAS, int EPI, bool OUT_BF16>
__global__ __launch_bounds__(512, 2) void gemm256(
    const u16* __restrict__ A, const u16* __restrict__ Bt, void* __restrict__ Cout,
    const float* __restrict__ bias, float* __restrict__ lsum,
    int M, int N, int K, int lda, int ldb, int ldc,
    long long aBatch, long long bBatch, long long cBatch, float scale) {
  __shared__ __align__(16) u16 As[2][256 * 64];   // 64 KB
  __shared__ __align__(16) u16 Bs[2][256 * 64];   // 64 KB  (128 KB -> 1 block/CU)
  const int tid = threadIdx.x;
  const int wave = tid >> 6, lane = tid & 63;
  const int quad = lane >> 4, lr = lane & 15;
  const int wm = (wave >> 2) * 128, wn = (wave & 3) * 64;
  const int row0 = blockIdx.x * 256, col0 = blockIdx.y * 256;
  A += (size_t)blockIdx.z * (size_t)aBatch;
  Bt += (size_t)blockIdx.z * (size_t)bBatch;

  f32x4 acc[8][4] = {};

  auto AsL = (__attribute__((address_space(3))) char*)&As[0][0];
  auto BsL = (__attribute__((address_space(3))) char*)&Bs[0][0];
  const char* Ab = (const char*)A;
  const char* Bb = (const char*)Bt;

  // one half-tile (128 rows x 64 bf16 = 16 KB) = 2 x global_load_lds(16B)/thread.
  // LDS dest linear (wave-uniform base + lane*16); XOR swizzle applied on the
  // GLOBAL source chunk: LDS[row][ch] <- global[row][ch ^ (row&7)] (16B chunks).
  auto stage_a = [&](int buf, int h, int k0) {
#pragma unroll
    for (int rr = 0; rr < 2; ++rr) {
      int chunk = rr * 512 + tid;            // 0..1023 = row*8 + chunkcol
      int row = chunk >> 3;
      int cs = (chunk & 7) ^ (row & 7);
      const void* g = Ab + (((size_t)(row0 + h * 128 + row) * lda +
                             (size_t)(k0 + cs * 8)) * 2);
      __builtin_amdgcn_global_load_lds(
          (const __attribute__((address_space(1))) void*)g,
          (__attribute__((address_space(3))) void*)(AsL + (size_t)buf * 32768 +
                                                   (size_t)(h * 1024 + chunk) * 16),
          16, 0, 0);
    }
  };
  auto stage_b = [&](int buf, int h, int k0) {
#pragma unroll
    for (int rr = 0; rr < 2; ++rr) {
      int chunk = rr * 512 + tid;
      int row = chunk >> 3;
      int cs = (chunk & 7) ^ (row & 7);
      const void* g = Bb + (((size_t)(col0 + h * 128 + row) * ldb +
                             (size_t)(k0 + cs * 8)) * 2);
      __builtin_amdgcn_global_load_lds(
          (const __attribute__((address_space(1))) void*)g,
          (__attribute__((address_space(3))) void*)(BsL + (size_t)buf * 32768 +
                                                   (size_t)(h * 1024 + chunk) * 16),
          16, 0, 0);
    }
  };

// register fragment reads; same 16x16 geometry as the measured-conflict-free kernel
#define READ_A(MH)                                                              \
  _Pragma("unroll") for (int ksi = 0; ksi < 2; ++ksi)                           \
  _Pragma("unroll") for (int i = 0; i < 4; ++i) {                               \
    int r = wm + ((MH) * 4 + i) * 16 + lr;                                      \
    int cc = (ksi * 4 + quad) ^ (r & 7);                                        \
    afr[ksi][i] = *(const bf16x8*)&As[cur][r * 64 + cc * 8];                    \
  }
#define READ_B(NH)                                                              \
  _Pragma("unroll") for (int ksi = 0; ksi < 2; ++ksi)                           \
  _Pragma("unroll") for (int j = 0; j < 2; ++j) {                               \
    int r = wn + ((NH) * 2 + j) * 16 + lr;                                      \
    int cc = (ksi * 4 + quad) ^ (r & 7);                                        \
    bfr[NH][j][ksi] = *(const bf16x8*)&Bs[cur][r * 64 + cc * 8];                \
  }
#define MFMA_QUAD(MH, NH)                                                       \
  _Pragma("unroll") for (int ksi = 0; ksi < 2; ++ksi)                           \
  _Pragma("unroll") for (int i = 0; i < 4; ++i)                                 \
  _Pragma("unroll") for (int j = 0; j < 2; ++j)                                 \
    acc[(MH) * 4 + i][(NH) * 2 + j] = __builtin_amdgcn_mfma_f32_16x16x32_bf16(  \
        afr[ksi][i], bfr[NH][j][ksi], acc[(MH) * 4 + i][(NH) * 2 + j], 0, 0, 0);

#define WAIT_LGKM()                                        \
  asm volatile("s_waitcnt lgkmcnt(0)" ::: "memory");       \
  __builtin_amdgcn_sched_barrier(0)

  const int nkt = K >> 6;

  // ---- prologue: stage tile 0 fully, drain, barrier
  stage_a(0, 0, 0);
  stage_b(0, 0, 0);
  stage_b(0, 1, 0);
  stage_a(0, 1, 0);
  asm volatile("s_waitcnt vmcnt(0)" ::: "memory");
  __builtin_amdgcn_sched_barrier(0);
  __builtin_amdgcn_s_barrier();

  bf16x8 afr[2][4];        // current m-half A frags (reloaded at phase 3)
  bf16x8 bfr[2][2][2];     // both n-halves of B, live across the tile

  for (int t = 0; t < nkt - 1; ++t) {
    const int cur = t & 1, nxt = cur ^ 1;
    const int kn = (t + 1) << 6;
    // ---- phase 1: quadrant (0,0); issue A0,B0 prefetch for t+1
    READ_A(0);
    READ_B(0);
    stage_a(nxt, 0, kn);
    stage_b(nxt, 0, kn);
    WAIT_LGKM();
    __builtin_amdgcn_s_setprio(1);
    MFMA_QUAD(0, 0);
    __builtin_amdgcn_s_setprio(0);
    // ---- phase 2: quadrant (0,1); issue B1,A1 prefetch for t+1
    READ_B(1);
    stage_b(nxt, 1, kn);
    stage_a(nxt, 1, kn);
    WAIT_LGKM();
    __builtin_amdgcn_s_setprio(1);
    MFMA_QUAD(0, 1);
    __builtin_amdgcn_s_setprio(0);
    // ---- phase 3: quadrant (1,0)
    READ_A(1);
    WAIT_LGKM();
    __builtin_amdgcn_s_setprio(1);
    MFMA_QUAD(1, 0);
    __builtin_amdgcn_s_setprio(0);
    // ---- phase 4: quadrant (1,1), pure regs
    __builtin_amdgcn_s_setprio(1);
    MFMA_QUAD(1, 1);
    __builtin_amdgcn_s_setprio(0);
    // ---- tile boundary: only t+1's loads outstanding (issued a tile ago) ->
    // vmcnt(0) is exact publication and nearly free; barrier syncs all waves.
    asm volatile("s_waitcnt vmcnt(0)" ::: "memory");
    __builtin_amdgcn_sched_barrier(0);
    __builtin_amdgcn_s_barrier();
  }
  // ---- peeled last tile: pure compute, no staging
  {
    const int cur = (nkt - 1) & 1;
    READ_A(0);
    READ_B(0);
    READ_B(1);
    WAIT_LGKM();
    MFMA_QUAD(0, 0);
    MFMA_QUAD(0, 1);
    READ_A(1);
    WAIT_LGKM();
    MFMA_QUAD(1, 0);
    MFMA_QUAD(1, 1);
  }
#undef READ_A
#undef READ_B
#undef MFMA_QUAD
#undef WAIT_LGKM

  // ---- epilogue. 16x16 C/D layout: col=lane&15, row=quad*4+reg (m89/m91-verified)
  const long long lrow0 = (long long)blockIdx.z * M + row0;

  if constexpr (EPI == 1) {
    u16* C = (u16*)Cout + (size_t)blockIdx.z * (size_t)cBatch;
#pragma unroll
    for (int i = 0; i < 8; ++i) {
#pragma unroll
      for (int ii = 0; ii < 4; ++ii) {
        int r = wm + i * 16 + quad * 4 + ii;
        float rowsum = 0.f;
#pragma unroll
        for (int j = 0; j < 4; ++j) {
          float e = __expf(acc[i][j][ii] * scale);
          rowsum += e;
          C[(size_t)(row0 + r) * ldc + (col0 + wn + j * 16 + lr)] = f2b(e);
        }
#pragma unroll
        for (int off = 1; off < 16; off <<= 1) rowsum += __shfl_xor(rowsum, off);
        if (lr == 0) atomicAdd(lsum + lrow0 + r, rowsum);
      }
    }
    return;
  }

#pragma unroll
  for (int i = 0; i < 8; ++i) {
#pragma unroll
    for (int ii = 0; ii < 4; ++ii) {
      int r = wm + i * 16 + quad * 4 + ii;
      float radd = 0.f, rmul = 1.f;
      if (BIAS == 2) radd = bias[row0 + r];
      if (EPI == 2) rmul = 1.0f / lsum[lrow0 + r];
#pragma unroll
      for (int j = 0; j < 4; ++j) {
        int c = col0 + wn + j * 16 + lr;
        float v = acc[i][j][ii] * rmul + radd;
        if (BIAS == 1) v += bias[c];
        if constexpr (OUT_BF16) {
          u16* C = (u16*)Cout + (size_t)blockIdx.z * (size_t)cBatch;
          C[(size_t)(row0 + r) * ldc + c] = f2b(v);
        } else {
          float* C = (float*)Cout + (size_t)blockIdx.z * (size_t)cBatch;
          C[(size_t)(row0 + r) * ldc + c] = v;
        }
      }
    }
  }
}

extern "C" void kernel_launch(void* const* d_in, const int* in_sizes, int n_in,
                              void* d_out, int out_size, void* d_ws, size_t ws_size,
                              hipStream_t stream) {
  const float* x = (const float*)d_in[0];
  const float* Wq = (const float*)d_in[1];
  const float* bq = (const float*)d_in[2];
  const float* Wk = (const float*)d_in[3];
  const float* bk = (const float*)d_in[4];
  const float* Wv = (const float*)d_in[5];
  const float* bv = (const float*)d_in[6];
  float* out = (float*)d_out;

  // workspace layout (bytes): total ~207 MB
  char* ws = (char*)d_ws;
  u16* xb = (u16*)ws;   ws += (size_t)M_TOTAL * D_DIM * 2;           // 33.5 MB
  u16* Wtqk = (u16*)ws; ws += (size_t)2 * H_DIM * D_DIM * 2;         // 4 MB
  u16* Wtv = (u16*)ws;  ws += (size_t)H_DIM * D_DIM * 2;             // 2 MB
  u16* QKm = (u16*)ws;  ws += (size_t)M_TOTAL * 2 * H_DIM * 2;       // 67 MB  [m][2048]
  u16* Vt = (u16*)ws;   ws += (size_t)BATCH * H_DIM * S_LEN * 2;     // 33.5 MB [b][h][s]
  u16* Sm = (u16*)ws;   ws += (size_t)BATCH * S_LEN * S_LEN * 2;     // 67 MB  [b][q][k]
  float* bqk = (float*)ws;  ws += 2048 * 4;
  float* lsum = (float*)ws; ws += (size_t)M_TOTAL * 4;               // 64 KB

  // 1) casts (+ bias concat + lsum zero, folded into wcast)
  cast_x_kernel<<<(M_TOTAL * D_DIM / 8 + 255) / 256, 256, 0, stream>>>(
      x, xb, M_TOTAL * D_DIM / 8);
  wcast_all_kernel<<<dim3(32, 32, 3), 256, 0, stream>>>(
      Wq, Wk, Wv, bq, bk, Wtqk, Wtv, bqk, lsum);

  // 2) [Q|K] = xb * Wtqk^T + bqk  (M=16384, N=2048, K=1024)
  gemm256<1, 0, true><<<dim3(64, 8, 1), 512, 0, stream>>>(
      xb, Wtqk, QKm, bqk, nullptr, M_TOTAL, 2 * H_DIM, D_DIM,
      D_DIM, D_DIM, 2 * H_DIM, 0, 0, 0, 0.f);

  // 3) Vt[b][h][s] = Wtv * xb_b^T + bv[row]  (M=1024, N=2048, K=1024, batched)
  gemm256<2, 0, true><<<dim3(4, 8, BATCH), 512, 0, stream>>>(
      Wtv, xb, Vt, bv, nullptr, H_DIM, S_LEN, D_DIM,
      D_DIM, D_DIM, S_LEN,
      0LL, (long long)S_LEN * D_DIM, (long long)H_DIM * S_LEN, 0.f);

  // 4) P_hat[b][q][k] = exp(Q_b K_b^T / 32) -> bf16, row sums -> lsum (batched)
  gemm256<0, 1, true><<<dim3(8, 8, BATCH), 512, 0, stream>>>(
      QKm, QKm + H_DIM, Sm, nullptr, lsum, S_LEN, S_LEN, H_DIM,
      2 * H_DIM, 2 * H_DIM, S_LEN,
      (long long)S_LEN * 2 * H_DIM, (long long)S_LEN * 2 * H_DIM,
      (long long)S_LEN * S_LEN, 0.03125f);

  // 5) out[b][q][h] = (P_hat_b / lsum) * Vt_b^T  (M=2048, N=1024, K=2048)
  gemm256<0, 2, false><<<dim3(8, 4, BATCH), 512, 0, stream>>>(
      Sm, Vt, out, nullptr, lsum, S_LEN, H_DIM, S_LEN,
      S_LEN, S_LEN, H_DIM,
      (long long)S_LEN * S_LEN, (long long)H_DIM * S_LEN,
      (long long)S_LEN * H_DIM, 0.f);
}